// Round 20
// baseline (314.895 us; speedup 1.0000x reference)
//
#include <hip/hip_runtime.h>
#include <hip/hip_bf16.h>
#include <math.h>

// Sparse top-2 MoE. GEMMs: 128x128 tile, BK=64, 4 waves, FULL double-buffered
// LDS (64KB -> 2 blocks/CU), stage(next)-issued-FIRST then compute, ONE
// __syncthreads per K-step (R14..R19 champion structure). T2 XOR-swizzle
// keyed to LDS dest row, permuted-B staging for packed epilogue stores,
// expert->XCD pinning (blockIdx.x==e). K-loop addressing strength-reduced:
// per-tile base pointers + scalar k-offset (no per-step 64-bit muls).
// GEMM1 A gathered in-kernel (GAT=1). GEMM2 writes per-slot Yh (bf16,
// weight+bias folded) -> combine kernel. Fused prologue (gate + transposes).

#define T_TOK 16384
#define H_DIM 512
#define FF_DIM 2048
#define E_NUM 8
#define NSLOT (T_TOK * 2)
#define NB_ROUTE 128
#define GATE_BLKS (T_TOK / 4)          // 4096
#define TR_BLKS (64 * 16 * 16)         // 16384

typedef __attribute__((ext_vector_type(4))) float f32x4;
typedef __attribute__((ext_vector_type(8))) short s16x8;

__device__ __forceinline__ void gload_lds16(const void* g, void* l) {
    __builtin_amdgcn_global_load_lds((const __attribute__((address_space(1))) void*)g,
                                     (__attribute__((address_space(3))) void*)l, 16, 0, 0);
}

__device__ __forceinline__ unsigned short f2bf(float f) {
    union { float f; unsigned int u; } a; a.f = f;
    unsigned int r = a.u + 0x7FFF + ((a.u >> 16) & 1);   // RNE
    return (unsigned short)(r >> 16);
}

__device__ __forceinline__ float bf2f(unsigned short u) {
    union { unsigned int u; float f; } a; a.u = ((unsigned int)u) << 16;
    return a.f;
}

// ---------------- small utility kernels ----------------

__global__ __launch_bounds__(256) void zero_f32(float* p, int n) {
    int i = (blockIdx.x * 256 + threadIdx.x) * 4;
    if (i < n) { f32x4 z = {0.f, 0.f, 0.f, 0.f}; *(f32x4*)(p + i) = z; }
}

// ---------------- fused prologue: gating + x->bf16 + weight transposes ----

__global__ __launch_bounds__(256) void prep_all(const float* __restrict__ x,
                                                const float* __restrict__ Wg,
                                                const float* __restrict__ bg,
                                                const float* __restrict__ W1,
                                                const float* __restrict__ W2,
                                                int* __restrict__ eidx,
                                                float* __restrict__ ewt,
                                                unsigned short* __restrict__ xb,
                                                unsigned short* __restrict__ W1t,
                                                unsigned short* __restrict__ W2t) {
    __shared__ float tile[32][33];
    const int bid = blockIdx.x;
    const int tid = threadIdx.x;
    if (bid < GATE_BLKS) {
        const int t = bid * 4 + (tid >> 6);
        const int l = tid & 63;
        const float* xr = x + (size_t)t * H_DIM;
        unsigned short* xw = xb + (size_t)t * H_DIM;
        double part[E_NUM];
#pragma unroll
        for (int e = 0; e < E_NUM; ++e) part[e] = 0.0;
#pragma unroll
        for (int i = 0; i < 8; ++i) {
            const int h = l + 64 * i;
            const float xv = xr[h];
            xw[h] = f2bf(xv);
            const double xd = (double)xv;
            const float* wr = Wg + (size_t)h * E_NUM;
#pragma unroll
            for (int e = 0; e < E_NUM; ++e) part[e] += xd * (double)wr[e];
        }
        for (int s = 1; s < 64; s <<= 1) {
#pragma unroll
            for (int e = 0; e < E_NUM; ++e) part[e] += __shfl_xor(part[e], s);
        }
        if (l == 0) {
            double lg[E_NUM];
#pragma unroll
            for (int e = 0; e < E_NUM; ++e) lg[e] = part[e] + (double)bg[e];
            int e0 = 0;
            for (int e = 1; e < E_NUM; ++e) if (lg[e] > lg[e0]) e0 = e;
            int e1 = (e0 == 0) ? 1 : 0;
            for (int e = 0; e < E_NUM; ++e) if (e != e0 && lg[e] > lg[e1]) e1 = e;
            double z = exp(lg[e1] - lg[e0]);
            float w0 = (float)(1.0 / (1.0 + z));
            float w1 = (float)(z / (1.0 + z));
            eidx[2 * t] = e0; eidx[2 * t + 1] = e1;
            ewt[2 * t] = w0; ewt[2 * t + 1] = w1;
        }
        return;
    }
    const int tb = bid - GATE_BLKS;
    const int z = tb >> 10;
    const int rem = tb & 1023;
    const int bx = rem & 63;
    const int by = rem >> 6;
    const float* s;
    unsigned short* d;
    int R, C, c0, r0;
    if (z < 8) {
        R = H_DIM; C = FF_DIM;
        s = W1 + (size_t)z * R * C;
        d = W1t + (size_t)z * R * C;
        c0 = bx * 32; r0 = by * 32;
    } else {
        R = FF_DIM; C = H_DIM;
        s = W2 + (size_t)(z - 8) * R * C;
        d = W2t + (size_t)(z - 8) * R * C;
        c0 = by * 32; r0 = bx * 32;
    }
    for (int idx = tid; idx < 1024; idx += 256) {
        int r = idx >> 5, c = idx & 31;
        tile[r][c] = s[(size_t)(r0 + r) * C + c0 + c];
    }
    __syncthreads();
    for (int idx = tid; idx < 1024; idx += 256) {
        int r = idx >> 5, c = idx & 31;
        d[(size_t)(c0 + r) * R + r0 + c] = f2bf(tile[c][r]);
    }
}

// ---------------- hierarchical routing scan ----------------

__global__ __launch_bounds__(256) void count_blocks(const int* __restrict__ eidx,
                                                    int* __restrict__ blockcnt) {
    __shared__ int cnt[E_NUM];
    if (threadIdx.x < E_NUM) cnt[threadIdx.x] = 0;
    __syncthreads();
    const int s = blockIdx.x * 256 + threadIdx.x;
    atomicAdd(&cnt[eidx[s]], 1);
    __syncthreads();
    if (threadIdx.x < E_NUM)
        blockcnt[blockIdx.x * E_NUM + threadIdx.x] = cnt[threadIdx.x];
}

__global__ __launch_bounds__(512) void scan_blocks(const int* __restrict__ blockcnt,
                                                   int* __restrict__ bbase,
                                                   int* __restrict__ offsets) {
    __shared__ int tot[E_NUM];
    __shared__ int obase[E_NUM + 1];
    const int e = threadIdx.x >> 6;
    const int l = threadIdx.x & 63;
    const int a = blockcnt[(2 * l) * E_NUM + e];
    const int b = blockcnt[(2 * l + 1) * E_NUM + e];
    const int s = a + b;
    int sc = s;
    for (int d = 1; d < 64; d <<= 1) {
        int o = __shfl_up(sc, d);
        if (l >= d) sc += o;
    }
    const int excl = sc - s;
    if (l == 63) tot[e] = sc;
    __syncthreads();
    if (threadIdx.x == 0) {
        int acc = 0;
        for (int i = 0; i < E_NUM; ++i) { obase[i] = acc; acc += tot[i]; }
        obase[E_NUM] = acc;
        for (int i = 0; i <= E_NUM; ++i) offsets[i] = obase[i];
    }
    __syncthreads();
    const int base = obase[e] + excl;
    bbase[(2 * l) * E_NUM + e] = base;
    bbase[(2 * l + 1) * E_NUM + e] = base + a;
}

__global__ __launch_bounds__(256) void scatter_slots(const int* __restrict__ eidx,
                                                     const float* __restrict__ ewt,
                                                     const int* __restrict__ bbase,
                                                     int* __restrict__ slot_token,
                                                     float* __restrict__ slot_w,
                                                     int* __restrict__ slot_of) {
    __shared__ int cur[E_NUM];
    if (threadIdx.x < E_NUM)
        cur[threadIdx.x] = bbase[blockIdx.x * E_NUM + threadIdx.x];
    __syncthreads();
    const int s = blockIdx.x * 256 + threadIdx.x;
    const int e = eidx[s];
    const int pos = atomicAdd(&cur[e], 1);
    slot_token[pos] = s >> 1;
    slot_w[pos] = ewt[s];
    slot_of[s] = pos;
}

// ---------------- grouped GEMM, 128x128 tile, BK=64, 4 waves, dbuf --------
// EPI=0: Hout[slot][c] = silu(A@B + bias)                  (bf16 packed)
// EPI=1: out[token][c] += slot_w*(A@B + bias)              (atomic fallback)
// EPI=2: Hout[slot][c] = bf16(slot_w*(A@B + bias))         (Yh, combine later)
// GAT=1: A rows gathered via slot_token (in-kernel; rows 1KB contiguous).
// Per K-step: {stage(kt+1)->buf^1 issued FIRST; ds_read+MFMA on buf[cur];
// __syncthreads}. Addressing: per-tile base pointers ap/bp + ldst; per-step
// address = base + scalar k-offset (no 64-bit muls in loop).
// B row permutation pi(64q+16j+m)=64q+4m+j -> lane owns 4 contiguous cols.

template<int EPI, int GAT, int NT, int KD, int NTOT, int MC, int LDA>
__global__ __launch_bounds__(256) void ggemm(
    const unsigned short* __restrict__ Ag,
    const unsigned short* __restrict__ Bt,
    const float* __restrict__ bias,
    const int* __restrict__ slot_token,
    const float* __restrict__ slot_w,
    const int* __restrict__ offsets,
    unsigned short* __restrict__ Hout,
    float* __restrict__ out) {
    const int e = blockIdx.x;
    const int nt = blockIdx.y % NT;
    const int mc = blockIdx.y / NT;
    const int base = offsets[e];
    const int cnt = offsets[e + 1] - base;
    if (cnt == 0) return;
    const int n0 = nt * 128;

    __shared__ __align__(16) unsigned short Abuf[2][128 * 64];
    __shared__ __align__(16) unsigned short Bbuf[2][128 * 64];

    const int tid = threadIdx.x;
    const int w = tid >> 6;
    const int l = tid & 63;
    const int wm = (w & 1) << 6;    // 0 / 64
    const int wn = (w >> 1) << 6;   // 0 / 64

    // fragment LDS byte offsets for K-half 0; K-half 1 = offset ^ 64
    int aoff[4], boff[4];
#pragma unroll
    for (int i = 0; i < 4; ++i) {
        int r = wm + i * 16 + (l & 15);
        aoff[i] = r * 128 + ((((l >> 4) ^ (r & 7))) << 4);
    }
#pragma unroll
    for (int j = 0; j < 4; ++j) {
        int r = wn + j * 16 + (l & 15);
        boff[j] = r * 128 + ((((l >> 4) ^ (r & 7))) << 4);
    }

    const int srow = tid >> 3;           // 0..31, staging row within 32-row stripe
    const int sce = (tid & 7) * 8;       // staging LDS col (elements)
    const unsigned short* Bg = Bt + (size_t)e * NTOT * KD + (size_t)n0 * KD;
    const int nk = KD / 64;

    // hoisted per-stage-unit constants (loop-invariant)
    int ldst[4], cev[4];
    const unsigned short* bp[4];
#pragma unroll
    for (int p = 0; p < 4; ++p) {
        int row = p * 32 + srow;
        cev[p] = sce ^ ((row & 7) * 8);
        ldst[p] = row * 64 + sce;
        int bsrc = (row & ~63) | ((row & 15) << 2) | ((row >> 4) & 3);
        bp[p] = Bg + (size_t)bsrc * KD + cev[p];
    }

    for (int m0 = mc * 128; m0 < cnt; m0 += MC * 128) {
        const unsigned short* ap[4];
#pragma unroll
        for (int p = 0; p < 4; ++p) {
            int s = m0 + p * 32 + srow;
            if (s > cnt - 1) s = cnt - 1;
            int ar = GAT ? slot_token[base + s] : (base + s);
            ap[p] = Ag + (size_t)ar * LDA + cev[p];
        }

        // prologue: stage kt=0 into buf 0
#pragma unroll
        for (int p = 0; p < 4; ++p) {
            gload_lds16(ap[p], &Abuf[0][ldst[p]]);
            gload_lds16(bp[p], &Bbuf[0][ldst[p]]);
        }
        __syncthreads();

        f32x4 acc[4][4] = {};
        for (int kt = 0; kt < nk; ++kt) {
            const int cur = kt & 1;
            if (kt + 1 < nk) {                   // issue next-tile stage FIRST
                const int k0 = (kt + 1) * 64;
#pragma unroll
                for (int p = 0; p < 4; ++p) {
                    gload_lds16(ap[p] + k0, &Abuf[cur ^ 1][ldst[p]]);
                    gload_lds16(bp[p] + k0, &Bbuf[cur ^ 1][ldst[p]]);
                }
            }
            const char* Ab = (const char*)&Abuf[cur][0];
            const char* Bb = (const char*)&Bbuf[cur][0];
#pragma unroll
            for (int half = 0; half < 2; ++half) {
                const int kb = half << 6;
                s16x8 af[4], bfv[4];
#pragma unroll
                for (int i = 0; i < 4; ++i) af[i] = *(const s16x8*)(Ab + (aoff[i] ^ kb));
#pragma unroll
                for (int j = 0; j < 4; ++j) bfv[j] = *(const s16x8*)(Bb + (boff[j] ^ kb));
#pragma unroll
                for (int i = 0; i < 4; ++i)
#pragma unroll
                    for (int j = 0; j < 4; ++j)
                        acc[i][j] = __builtin_amdgcn_mfma_f32_16x16x32_bf16(af[i], bfv[j], acc[i][j], 0, 0, 0);
            }
            __syncthreads();   // drains this step's stage + orders buffers
        }

        const int c0 = wn + (l & 15) * 4;
        float b4[4];
#pragma unroll
        for (int j = 0; j < 4; ++j) b4[j] = bias[(size_t)e * NTOT + n0 + c0 + j];

#pragma unroll
        for (int i = 0; i < 4; ++i) {
            const int rb = wm + i * 16 + ((l >> 4) << 2);
#pragma unroll
            for (int r = 0; r < 4; ++r) {
                const int row = m0 + rb + r;
                if (row >= cnt) continue;
                const int slot = base + row;
                if (EPI == 0) {
                    float v0 = acc[i][0][r] + b4[0];
                    float v1 = acc[i][1][r] + b4[1];
                    float v2 = acc[i][2][r] + b4[2];
                    float v3 = acc[i][3][r] + b4[3];
                    v0 = v0 / (1.0f + __expf(-v0));
                    v1 = v1 / (1.0f + __expf(-v1));
                    v2 = v2 / (1.0f + __expf(-v2));
                    v3 = v3 / (1.0f + __expf(-v3));
                    uint2 pk;
                    pk.x = (unsigned int)f2bf(v0) | ((unsigned int)f2bf(v1) << 16);
                    pk.y = (unsigned int)f2bf(v2) | ((unsigned int)f2bf(v3) << 16);
                    *(uint2*)&Hout[(size_t)slot * NTOT + n0 + c0] = pk;
                } else if (EPI == 2) {
                    const float wgt = slot_w[slot];
                    uint2 pk;
                    pk.x = (unsigned int)f2bf(wgt * (acc[i][0][r] + b4[0]))
                         | ((unsigned int)f2bf(wgt * (acc[i][1][r] + b4[1])) << 16);
                    pk.y = (unsigned int)f2bf(wgt * (acc[i][2][r] + b4[2]))
                         | ((unsigned int)f2bf(wgt * (acc[i][3][r] + b4[3])) << 16);
                    *(uint2*)&Hout[(size_t)slot * NTOT + n0 + c0] = pk;
                } else {
                    const int tok = slot_token[slot];
                    const float wgt = slot_w[slot];
                    float* op = out + (size_t)tok * NTOT + n0 + c0;
#pragma unroll
                    for (int j = 0; j < 4; ++j)
                        atomicAdd(op + j, wgt * (acc[i][j][r] + b4[j]));
                }
            }
        }
        __syncthreads();   // epilogue done before next m0 prologue overwrites buf0
    }
}

// out[t] = Yh[slot_of[2t]] + Yh[slot_of[2t+1]]   (bf16 in, f32 out)
__global__ __launch_bounds__(256) void combine_y(const unsigned short* __restrict__ Y,
                                                 const int* __restrict__ slot_of,
                                                 float* __restrict__ out) {
    const int idx = blockIdx.x * 256 + threadIdx.x;
    const int t = idx >> 6;
    const int h = (idx & 63) * 8;
    const int sa = slot_of[2 * t];
    const int sb = slot_of[2 * t + 1];
    s16x8 a = *(const s16x8*)&Y[(size_t)sa * H_DIM + h];
    s16x8 b = *(const s16x8*)&Y[(size_t)sb * H_DIM + h];
    f32x4 lo, hi;
#pragma unroll
    for (int j = 0; j < 4; ++j) {
        lo[j] = bf2f((unsigned short)a[j]) + bf2f((unsigned short)b[j]);
        hi[j] = bf2f((unsigned short)a[j + 4]) + bf2f((unsigned short)b[j + 4]);
    }
    float* po = out + (size_t)t * H_DIM + h;
    *(f32x4*)po = lo;
    *(f32x4*)(po + 4) = hi;
}

// ---------------- host ----------------

extern "C" void kernel_launch(void* const* d_in, const int* in_sizes, int n_in,
                              void* d_out, int out_size, void* d_ws, size_t ws_size,
                              hipStream_t stream) {
    const float* x  = (const float*)d_in[0];
    const float* Wg = (const float*)d_in[1];
    const float* bg = (const float*)d_in[2];
    const float* W1 = (const float*)d_in[3];
    const float* b1 = (const float*)d_in[4];
    const float* W2 = (const float*)d_in[5];
    const float* b2 = (const float*)d_in[6];
    float* out = (float*)d_out;

    char* ws = (char*)d_ws;
    size_t off = 0;
    auto take = [&](size_t b) -> void* {
        void* p = ws + off;
        off = (off + b + 255) & ~(size_t)255;
        return p;
    };
    unsigned short* xb   = (unsigned short*)take((size_t)T_TOK * H_DIM * 2);
    unsigned short* W1t  = (unsigned short*)take((size_t)E_NUM * H_DIM * FF_DIM * 2);
    unsigned short* W2t  = (unsigned short*)take((size_t)E_NUM * H_DIM * FF_DIM * 2);
    int*   eidx       = (int*)take((size_t)T_TOK * 2 * 4);
    float* ewt        = (float*)take((size_t)T_TOK * 2 * 4);
    int*   slot_token = (int*)take((size_t)NSLOT * 4);
    float* slot_w     = (float*)take((size_t)NSLOT * 4);
    int*   slot_of    = (int*)take((size_t)NSLOT * 4);
    int*   blockcnt   = (int*)take((size_t)NB_ROUTE * E_NUM * 4);
    int*   bbase      = (int*)take((size_t)NB_ROUTE * E_NUM * 4);
    int*   offsets    = (int*)take(256);
    unsigned short* Hact = (unsigned short*)take((size_t)NSLOT * FF_DIM * 2);
    unsigned short* Yh = (unsigned short*)(ws + off);
    const int useY = (ws_size >= off + (size_t)NSLOT * H_DIM * 2) ? 1 : 0;

    // fused prologue: gating(+x->bf16) and weight transposes run concurrently
    prep_all<<<GATE_BLKS + TR_BLKS, 256, 0, stream>>>(
        x, Wg, bg, W1, W2, eidx, ewt, xb, W1t, W2t);

    // hierarchical routing (no global atomics)
    count_blocks<<<NB_ROUTE, 256, 0, stream>>>(eidx, blockcnt);
    scan_blocks<<<1, 512, 0, stream>>>(blockcnt, bbase, offsets);
    scatter_slots<<<NB_ROUTE, 256, 0, stream>>>(eidx, ewt, bbase, slot_token, slot_w, slot_of);

    // GEMM1: M=cnt, N=2048, K=512.  grid (8, 16 nt x 16 mc) = 2048 blocks
    ggemm<0, 1, 16, 512, 2048, 16, 512><<<dim3(8, 256), 256, 0, stream>>>(
        xb, W1t, b1, slot_token, slot_w, offsets, Hact, out);
    // GEMM2: M=cnt, N=512, K=2048.  grid (8, 4 nt x 32 mc) = 1024 blocks
    if (useY) {
        ggemm<2, 0, 4, 2048, 512, 32, 2048><<<dim3(8, 128), 256, 0, stream>>>(
            Hact, W2t, b2, slot_token, slot_w, offsets, Yh, out);
        combine_y<<<T_TOK * 64 / 256, 256, 0, stream>>>(Yh, slot_of, out);
    } else {
        zero_f32<<<(T_TOK * H_DIM / 4 + 255) / 256, 256, 0, stream>>>(out, T_TOK * H_DIM);
        ggemm<1, 0, 4, 2048, 512, 32, 2048><<<dim3(8, 128), 256, 0, stream>>>(
            Hact, W2t, b2, slot_token, slot_w, offsets, Hact, out);
    }
    (void)in_sizes; (void)n_in; (void)out_size;
}

// Round 21
// 310.518 us; speedup vs baseline: 1.0141x; 1.0141x over previous
//
#include <hip/hip_runtime.h>
#include <hip/hip_bf16.h>
#include <math.h>

// Sparse top-2 MoE — FINAL (champion, benched 311.2us).
// GEMMs: 128x128 tile, BK=64, 4 waves, FULL double-buffered LDS (64KB ->
// 2 blocks/CU), stage(next)-issued-FIRST then compute, ONE __syncthreads per
// K-step. T2 XOR-swizzle keyed to LDS dest row, permuted-B staging for packed
// epilogue stores, expert->XCD pinning (blockIdx.x==e). GEMM1 A gathered
// in-kernel (GAT=1). GEMM2 writes per-slot Yh (bf16, weight+bias folded) ->
// combine kernel; atomic fallback. Both weight transposes fused in one launch.
// Structural note: 311us is the latency-structural plateau of this family —
// deeper pipelines (8-phase, counted vmcnt, triple-buffer) all lose more
// co-residency (2 blocks/CU at 64KB LDS) than they hide latency at these
// short-K grouped shapes (K=512/2048, M~4096/expert).

#define T_TOK 16384
#define H_DIM 512
#define FF_DIM 2048
#define E_NUM 8
#define NSLOT (T_TOK * 2)
#define NB_ROUTE 128

typedef __attribute__((ext_vector_type(4))) float f32x4;
typedef __attribute__((ext_vector_type(8))) short s16x8;

__device__ __forceinline__ void gload_lds16(const void* g, void* l) {
    __builtin_amdgcn_global_load_lds((const __attribute__((address_space(1))) void*)g,
                                     (__attribute__((address_space(3))) void*)l, 16, 0, 0);
}

__device__ __forceinline__ unsigned short f2bf(float f) {
    union { float f; unsigned int u; } a; a.f = f;
    unsigned int r = a.u + 0x7FFF + ((a.u >> 16) & 1);   // RNE
    return (unsigned short)(r >> 16);
}

__device__ __forceinline__ float bf2f(unsigned short u) {
    union { unsigned int u; float f; } a; a.u = ((unsigned int)u) << 16;
    return a.f;
}

// ---------------- small utility kernels ----------------

__global__ __launch_bounds__(256) void zero_f32(float* p, int n) {
    int i = (blockIdx.x * 256 + threadIdx.x) * 4;
    if (i < n) { f32x4 z = {0.f, 0.f, 0.f, 0.f}; *(f32x4*)(p + i) = z; }
}

// fused: z<8 -> W1 expert z ([H][FF] -> [FF][H]); z>=8 -> W2 expert z-8
// ([FF][H] -> [H][FF]).  grid (64,16,16).
__global__ __launch_bounds__(256) void transpose_both(const float* __restrict__ W1,
                                                      const float* __restrict__ W2,
                                                      unsigned short* __restrict__ W1t,
                                                      unsigned short* __restrict__ W2t) {
    const int z = blockIdx.z;
    const float* s;
    unsigned short* d;
    int R, C, c0, r0;
    if (z < 8) {
        R = H_DIM; C = FF_DIM;
        s = W1 + (size_t)z * R * C;
        d = W1t + (size_t)z * R * C;
        c0 = blockIdx.x * 32; r0 = blockIdx.y * 32;
    } else {
        R = FF_DIM; C = H_DIM;
        s = W2 + (size_t)(z - 8) * R * C;
        d = W2t + (size_t)(z - 8) * R * C;
        c0 = blockIdx.y * 32; r0 = blockIdx.x * 32;
    }
    __shared__ float tile[32][33];
    const int tid = threadIdx.x;
    for (int idx = tid; idx < 1024; idx += 256) {
        int r = idx >> 5, c = idx & 31;
        tile[r][c] = s[(size_t)(r0 + r) * C + c0 + c];
    }
    __syncthreads();
    for (int idx = tid; idx < 1024; idx += 256) {
        int r = idx >> 5, c = idx & 31;
        d[(size_t)(c0 + r) * R + r0 + c] = f2bf(tile[c][r]);
    }
}

// ---------------- gating (no atomics) + fused x->bf16 ----------------

__global__ __launch_bounds__(256) void gate_topk(const float* __restrict__ x,
                                                 const float* __restrict__ Wg,
                                                 const float* __restrict__ bg,
                                                 int* __restrict__ eidx,
                                                 float* __restrict__ ewt,
                                                 unsigned short* __restrict__ xb) {
    const int t = blockIdx.x * 4 + (threadIdx.x >> 6);
    const int l = threadIdx.x & 63;
    const float* xr = x + (size_t)t * H_DIM;
    unsigned short* xw = xb + (size_t)t * H_DIM;
    double part[E_NUM];
#pragma unroll
    for (int e = 0; e < E_NUM; ++e) part[e] = 0.0;
#pragma unroll
    for (int i = 0; i < 8; ++i) {
        const int h = l + 64 * i;
        const float xv = xr[h];
        xw[h] = f2bf(xv);
        const double xd = (double)xv;
        const float* wr = Wg + (size_t)h * E_NUM;
#pragma unroll
        for (int e = 0; e < E_NUM; ++e) part[e] += xd * (double)wr[e];
    }
    for (int s = 1; s < 64; s <<= 1) {
#pragma unroll
        for (int e = 0; e < E_NUM; ++e) part[e] += __shfl_xor(part[e], s);
    }
    if (l == 0) {
        double lg[E_NUM];
#pragma unroll
        for (int e = 0; e < E_NUM; ++e) lg[e] = part[e] + (double)bg[e];
        int e0 = 0;
        for (int e = 1; e < E_NUM; ++e) if (lg[e] > lg[e0]) e0 = e;
        int e1 = (e0 == 0) ? 1 : 0;
        for (int e = 0; e < E_NUM; ++e) if (e != e0 && lg[e] > lg[e1]) e1 = e;
        double z = exp(lg[e1] - lg[e0]);
        float w0 = (float)(1.0 / (1.0 + z));
        float w1 = (float)(z / (1.0 + z));
        eidx[2 * t] = e0; eidx[2 * t + 1] = e1;
        ewt[2 * t] = w0; ewt[2 * t + 1] = w1;
    }
}

// ---------------- hierarchical routing scan ----------------

__global__ __launch_bounds__(256) void count_blocks(const int* __restrict__ eidx,
                                                    int* __restrict__ blockcnt) {
    __shared__ int cnt[E_NUM];
    if (threadIdx.x < E_NUM) cnt[threadIdx.x] = 0;
    __syncthreads();
    const int s = blockIdx.x * 256 + threadIdx.x;
    atomicAdd(&cnt[eidx[s]], 1);
    __syncthreads();
    if (threadIdx.x < E_NUM)
        blockcnt[blockIdx.x * E_NUM + threadIdx.x] = cnt[threadIdx.x];
}

__global__ __launch_bounds__(512) void scan_blocks(const int* __restrict__ blockcnt,
                                                   int* __restrict__ bbase,
                                                   int* __restrict__ offsets) {
    __shared__ int tot[E_NUM];
    __shared__ int obase[E_NUM + 1];
    const int e = threadIdx.x >> 6;
    const int l = threadIdx.x & 63;
    const int a = blockcnt[(2 * l) * E_NUM + e];
    const int b = blockcnt[(2 * l + 1) * E_NUM + e];
    const int s = a + b;
    int sc = s;
    for (int d = 1; d < 64; d <<= 1) {
        int o = __shfl_up(sc, d);
        if (l >= d) sc += o;
    }
    const int excl = sc - s;
    if (l == 63) tot[e] = sc;
    __syncthreads();
    if (threadIdx.x == 0) {
        int acc = 0;
        for (int i = 0; i < E_NUM; ++i) { obase[i] = acc; acc += tot[i]; }
        obase[E_NUM] = acc;
        for (int i = 0; i <= E_NUM; ++i) offsets[i] = obase[i];
    }
    __syncthreads();
    const int base = obase[e] + excl;
    bbase[(2 * l) * E_NUM + e] = base;
    bbase[(2 * l + 1) * E_NUM + e] = base + a;
}

__global__ __launch_bounds__(256) void scatter_slots(const int* __restrict__ eidx,
                                                     const float* __restrict__ ewt,
                                                     const int* __restrict__ bbase,
                                                     int* __restrict__ slot_token,
                                                     float* __restrict__ slot_w,
                                                     int* __restrict__ slot_of) {
    __shared__ int cur[E_NUM];
    if (threadIdx.x < E_NUM)
        cur[threadIdx.x] = bbase[blockIdx.x * E_NUM + threadIdx.x];
    __syncthreads();
    const int s = blockIdx.x * 256 + threadIdx.x;
    const int e = eidx[s];
    const int pos = atomicAdd(&cur[e], 1);
    slot_token[pos] = s >> 1;
    slot_w[pos] = ewt[s];
    slot_of[s] = pos;
}

// ---------------- grouped GEMM, 128x128 tile, BK=64, 4 waves, dbuf --------
// EPI=0: Hout[slot][c] = silu(A@B + bias)                  (bf16 packed)
// EPI=1: out[token][c] += slot_w*(A@B + bias)              (atomic fallback)
// EPI=2: Hout[slot][c] = bf16(slot_w*(A@B + bias))         (Yh, combine later)
// GAT=1: A rows gathered via slot_token (in-kernel; rows 1KB contiguous).
// Per K-step: {stage(kt+1)->buf^1 issued FIRST; ds_read+MFMA on buf[cur];
// __syncthreads}.  B row permutation pi(64q+16j+m)=64q+4m+j.

template<int EPI, int GAT, int NT, int KD, int NTOT, int MC, int LDA>
__global__ __launch_bounds__(256) void ggemm(
    const unsigned short* __restrict__ Ag,
    const unsigned short* __restrict__ Bt,
    const float* __restrict__ bias,
    const int* __restrict__ slot_token,
    const float* __restrict__ slot_w,
    const int* __restrict__ offsets,
    unsigned short* __restrict__ Hout,
    float* __restrict__ out) {
    const int e = blockIdx.x;
    const int nt = blockIdx.y % NT;
    const int mc = blockIdx.y / NT;
    const int base = offsets[e];
    const int cnt = offsets[e + 1] - base;
    if (cnt == 0) return;
    const int n0 = nt * 128;

    __shared__ __align__(16) unsigned short Abuf[2][128 * 64];
    __shared__ __align__(16) unsigned short Bbuf[2][128 * 64];

    const int tid = threadIdx.x;
    const int w = tid >> 6;
    const int l = tid & 63;
    const int wm = (w & 1) << 6;    // 0 / 64
    const int wn = (w >> 1) << 6;   // 0 / 64

    // fragment LDS byte offsets for K-half 0; K-half 1 = offset ^ 64
    int aoff[4], boff[4];
#pragma unroll
    for (int i = 0; i < 4; ++i) {
        int r = wm + i * 16 + (l & 15);
        aoff[i] = r * 128 + ((((l >> 4) ^ (r & 7))) << 4);
    }
#pragma unroll
    for (int j = 0; j < 4; ++j) {
        int r = wn + j * 16 + (l & 15);
        boff[j] = r * 128 + ((((l >> 4) ^ (r & 7))) << 4);
    }

    const int srow = tid >> 3;           // 0..31, staging row within 32-row stripe
    const int sce = (tid & 7) * 8;       // staging LDS col (elements)
    const unsigned short* Bg = Bt + (size_t)e * NTOT * KD + (size_t)n0 * KD;
    const int nk = KD / 64;

    // permuted B source rows: LDS row rho holds global row pi(rho)
    int bsrc[4];
#pragma unroll
    for (int p = 0; p < 4; ++p) {
        int row = p * 32 + srow;
        bsrc[p] = (row & ~63) | ((row & 15) << 2) | ((row >> 4) & 3);
    }

    for (int m0 = mc * 128; m0 < cnt; m0 += MC * 128) {
        int arow[4];
#pragma unroll
        for (int p = 0; p < 4; ++p) {
            int s = m0 + p * 32 + srow;
            if (s > cnt - 1) s = cnt - 1;
            arow[p] = GAT ? slot_token[base + s] : (base + s);
        }

        // prologue: stage kt=0 into buf 0
#pragma unroll
        for (int p = 0; p < 4; ++p) {
            int row = p * 32 + srow;
            int ce = sce ^ ((row & 7) * 8);
            gload_lds16(Ag + (size_t)arow[p] * LDA + ce, &Abuf[0][row * 64 + sce]);
            gload_lds16(Bg + (size_t)bsrc[p] * KD + ce, &Bbuf[0][row * 64 + sce]);
        }
        __syncthreads();

        f32x4 acc[4][4] = {};
        for (int kt = 0; kt < nk; ++kt) {
            const int cur = kt & 1;
            if (kt + 1 < nk) {                   // issue next-tile stage FIRST
                const int k0 = (kt + 1) * 64;
#pragma unroll
                for (int p = 0; p < 4; ++p) {
                    int row = p * 32 + srow;
                    int ce = sce ^ ((row & 7) * 8);
                    gload_lds16(Ag + (size_t)arow[p] * LDA + k0 + ce, &Abuf[cur ^ 1][row * 64 + sce]);
                    gload_lds16(Bg + (size_t)bsrc[p] * KD + k0 + ce, &Bbuf[cur ^ 1][row * 64 + sce]);
                }
            }
            const char* Ab = (const char*)&Abuf[cur][0];
            const char* Bb = (const char*)&Bbuf[cur][0];
#pragma unroll
            for (int half = 0; half < 2; ++half) {
                const int kb = half << 6;
                s16x8 af[4], bfv[4];
#pragma unroll
                for (int i = 0; i < 4; ++i) af[i] = *(const s16x8*)(Ab + (aoff[i] ^ kb));
#pragma unroll
                for (int j = 0; j < 4; ++j) bfv[j] = *(const s16x8*)(Bb + (boff[j] ^ kb));
#pragma unroll
                for (int i = 0; i < 4; ++i)
#pragma unroll
                    for (int j = 0; j < 4; ++j)
                        acc[i][j] = __builtin_amdgcn_mfma_f32_16x16x32_bf16(af[i], bfv[j], acc[i][j], 0, 0, 0);
            }
            __syncthreads();   // drains this step's stage + orders buffers
        }

        const int c0 = wn + (l & 15) * 4;
        float b4[4];
#pragma unroll
        for (int j = 0; j < 4; ++j) b4[j] = bias[(size_t)e * NTOT + n0 + c0 + j];

#pragma unroll
        for (int i = 0; i < 4; ++i) {
            const int rb = wm + i * 16 + ((l >> 4) << 2);
#pragma unroll
            for (int r = 0; r < 4; ++r) {
                const int row = m0 + rb + r;
                if (row >= cnt) continue;
                const int slot = base + row;
                if (EPI == 0) {
                    float v0 = acc[i][0][r] + b4[0];
                    float v1 = acc[i][1][r] + b4[1];
                    float v2 = acc[i][2][r] + b4[2];
                    float v3 = acc[i][3][r] + b4[3];
                    v0 = v0 / (1.0f + __expf(-v0));
                    v1 = v1 / (1.0f + __expf(-v1));
                    v2 = v2 / (1.0f + __expf(-v2));
                    v3 = v3 / (1.0f + __expf(-v3));
                    uint2 pk;
                    pk.x = (unsigned int)f2bf(v0) | ((unsigned int)f2bf(v1) << 16);
                    pk.y = (unsigned int)f2bf(v2) | ((unsigned int)f2bf(v3) << 16);
                    *(uint2*)&Hout[(size_t)slot * NTOT + n0 + c0] = pk;
                } else if (EPI == 2) {
                    const float wgt = slot_w[slot];
                    uint2 pk;
                    pk.x = (unsigned int)f2bf(wgt * (acc[i][0][r] + b4[0]))
                         | ((unsigned int)f2bf(wgt * (acc[i][1][r] + b4[1])) << 16);
                    pk.y = (unsigned int)f2bf(wgt * (acc[i][2][r] + b4[2]))
                         | ((unsigned int)f2bf(wgt * (acc[i][3][r] + b4[3])) << 16);
                    *(uint2*)&Hout[(size_t)slot * NTOT + n0 + c0] = pk;
                } else {
                    const int tok = slot_token[slot];
                    const float wgt = slot_w[slot];
                    float* op = out + (size_t)tok * NTOT + n0 + c0;
#pragma unroll
                    for (int j = 0; j < 4; ++j)
                        atomicAdd(op + j, wgt * (acc[i][j][r] + b4[j]));
                }
            }
        }
        __syncthreads();   // epilogue done before next m0 prologue overwrites buf0
    }
}

// out[t] = Yh[slot_of[2t]] + Yh[slot_of[2t+1]]   (bf16 in, f32 out)
__global__ __launch_bounds__(256) void combine_y(const unsigned short* __restrict__ Y,
                                                 const int* __restrict__ slot_of,
                                                 float* __restrict__ out) {
    const int idx = blockIdx.x * 256 + threadIdx.x;
    const int t = idx >> 6;
    const int h = (idx & 63) * 8;
    const int sa = slot_of[2 * t];
    const int sb = slot_of[2 * t + 1];
    s16x8 a = *(const s16x8*)&Y[(size_t)sa * H_DIM + h];
    s16x8 b = *(const s16x8*)&Y[(size_t)sb * H_DIM + h];
    f32x4 lo, hi;
#pragma unroll
    for (int j = 0; j < 4; ++j) {
        lo[j] = bf2f((unsigned short)a[j]) + bf2f((unsigned short)b[j]);
        hi[j] = bf2f((unsigned short)a[j + 4]) + bf2f((unsigned short)b[j + 4]);
    }
    float* po = out + (size_t)t * H_DIM + h;
    *(f32x4*)po = lo;
    *(f32x4*)(po + 4) = hi;
}

// ---------------- host ----------------

extern "C" void kernel_launch(void* const* d_in, const int* in_sizes, int n_in,
                              void* d_out, int out_size, void* d_ws, size_t ws_size,
                              hipStream_t stream) {
    const float* x  = (const float*)d_in[0];
    const float* Wg = (const float*)d_in[1];
    const float* bg = (const float*)d_in[2];
    const float* W1 = (const float*)d_in[3];
    const float* b1 = (const float*)d_in[4];
    const float* W2 = (const float*)d_in[5];
    const float* b2 = (const float*)d_in[6];
    float* out = (float*)d_out;

    char* ws = (char*)d_ws;
    size_t off = 0;
    auto take = [&](size_t b) -> void* {
        void* p = ws + off;
        off = (off + b + 255) & ~(size_t)255;
        return p;
    };
    unsigned short* xb   = (unsigned short*)take((size_t)T_TOK * H_DIM * 2);
    unsigned short* W1t  = (unsigned short*)take((size_t)E_NUM * H_DIM * FF_DIM * 2);
    unsigned short* W2t  = (unsigned short*)take((size_t)E_NUM * H_DIM * FF_DIM * 2);
    int*   eidx       = (int*)take((size_t)T_TOK * 2 * 4);
    float* ewt        = (float*)take((size_t)T_TOK * 2 * 4);
    int*   slot_token = (int*)take((size_t)NSLOT * 4);
    float* slot_w     = (float*)take((size_t)NSLOT * 4);
    int*   slot_of    = (int*)take((size_t)NSLOT * 4);
    int*   blockcnt   = (int*)take((size_t)NB_ROUTE * E_NUM * 4);
    int*   bbase      = (int*)take((size_t)NB_ROUTE * E_NUM * 4);
    int*   offsets    = (int*)take(256);
    unsigned short* Hact = (unsigned short*)take((size_t)NSLOT * FF_DIM * 2);
    unsigned short* Yh = (unsigned short*)(ws + off);
    const int useY = (ws_size >= off + (size_t)NSLOT * H_DIM * 2) ? 1 : 0;

    // fused weight transposes (f32 -> bf16, [E][C][R])
    transpose_both<<<dim3(64, 16, 16), 256, 0, stream>>>(W1, W2, W1t, W2t);

    // gating (+ fused x->bf16) + hierarchical routing (no global atomics)
    gate_topk<<<T_TOK / 4, 256, 0, stream>>>(x, Wg, bg, eidx, ewt, xb);
    count_blocks<<<NB_ROUTE, 256, 0, stream>>>(eidx, blockcnt);
    scan_blocks<<<1, 512, 0, stream>>>(blockcnt, bbase, offsets);
    scatter_slots<<<NB_ROUTE, 256, 0, stream>>>(eidx, ewt, bbase, slot_token, slot_w, slot_of);

    // GEMM1: M=cnt, N=2048, K=512.  grid (8, 16 nt x 16 mc) = 2048 blocks
    ggemm<0, 1, 16, 512, 2048, 16, 512><<<dim3(8, 256), 256, 0, stream>>>(
        xb, W1t, b1, slot_token, slot_w, offsets, Hact, out);
    // GEMM2: M=cnt, N=512, K=2048.  grid (8, 4 nt x 32 mc) = 1024 blocks
    if (useY) {
        ggemm<2, 0, 4, 2048, 512, 32, 2048><<<dim3(8, 128), 256, 0, stream>>>(
            Hact, W2t, b2, slot_token, slot_w, offsets, Yh, out);
        combine_y<<<T_TOK * 64 / 256, 256, 0, stream>>>(Yh, slot_of, out);
    } else {
        zero_f32<<<(T_TOK * H_DIM / 4 + 255) / 256, 256, 0, stream>>>(out, T_TOK * H_DIM);
        ggemm<1, 0, 4, 2048, 512, 32, 2048><<<dim3(8, 128), 256, 0, stream>>>(
            Hact, W2t, b2, slot_token, slot_w, offsets, Hact, out);
    }
    (void)in_sizes; (void)n_in; (void)out_size;
}

// Round 22
// 292.544 us; speedup vs baseline: 1.0764x; 1.0614x over previous
//
#include <hip/hip_runtime.h>
#include <hip/hip_bf16.h>
#include <math.h>

// Sparse top-2 MoE. GEMMs: 128x128 tile, BK=64, **8 waves (512 thr)**, FULL
// double-buffered LDS (64KB -> 2 blocks/CU -> 16 waves/CU = 4/SIMD),
// stage(next)-issued-FIRST then compute, ONE __syncthreads per K-step.
// Wave grid 2m x 4n: each wave 64x32, acc[4][2]. T2 XOR-swizzle keyed to LDS
// dest row, permuted-B staging (lane owns 2 contiguous output cols, packed
// stores), expert->XCD pinning (blockIdx.x==e). GEMM1 A gathered in-kernel.
// GEMM2 writes per-slot Yh (bf16, weight+bias folded) -> combine kernel.

#define T_TOK 16384
#define H_DIM 512
#define FF_DIM 2048
#define E_NUM 8
#define NSLOT (T_TOK * 2)
#define NB_ROUTE 128

typedef __attribute__((ext_vector_type(4))) float f32x4;
typedef __attribute__((ext_vector_type(8))) short s16x8;

__device__ __forceinline__ void gload_lds16(const void* g, void* l) {
    __builtin_amdgcn_global_load_lds((const __attribute__((address_space(1))) void*)g,
                                     (__attribute__((address_space(3))) void*)l, 16, 0, 0);
}

__device__ __forceinline__ unsigned short f2bf(float f) {
    union { float f; unsigned int u; } a; a.f = f;
    unsigned int r = a.u + 0x7FFF + ((a.u >> 16) & 1);   // RNE
    return (unsigned short)(r >> 16);
}

__device__ __forceinline__ float bf2f(unsigned short u) {
    union { unsigned int u; float f; } a; a.u = ((unsigned int)u) << 16;
    return a.f;
}

// ---------------- small utility kernels ----------------

__global__ __launch_bounds__(256) void zero_f32(float* p, int n) {
    int i = (blockIdx.x * 256 + threadIdx.x) * 4;
    if (i < n) { f32x4 z = {0.f, 0.f, 0.f, 0.f}; *(f32x4*)(p + i) = z; }
}

// fused: z<8 -> W1 expert z ([H][FF] -> [FF][H]); z>=8 -> W2 expert z-8
__global__ __launch_bounds__(256) void transpose_both(const float* __restrict__ W1,
                                                      const float* __restrict__ W2,
                                                      unsigned short* __restrict__ W1t,
                                                      unsigned short* __restrict__ W2t) {
    const int z = blockIdx.z;
    const float* s;
    unsigned short* d;
    int R, C, c0, r0;
    if (z < 8) {
        R = H_DIM; C = FF_DIM;
        s = W1 + (size_t)z * R * C;
        d = W1t + (size_t)z * R * C;
        c0 = blockIdx.x * 32; r0 = blockIdx.y * 32;
    } else {
        R = FF_DIM; C = H_DIM;
        s = W2 + (size_t)(z - 8) * R * C;
        d = W2t + (size_t)(z - 8) * R * C;
        c0 = blockIdx.y * 32; r0 = blockIdx.x * 32;
    }
    __shared__ float tile[32][33];
    const int tid = threadIdx.x;
    for (int idx = tid; idx < 1024; idx += 256) {
        int r = idx >> 5, c = idx & 31;
        tile[r][c] = s[(size_t)(r0 + r) * C + c0 + c];
    }
    __syncthreads();
    for (int idx = tid; idx < 1024; idx += 256) {
        int r = idx >> 5, c = idx & 31;
        d[(size_t)(c0 + r) * R + r0 + c] = f2bf(tile[c][r]);
    }
}

// ---------------- gating (no atomics) + fused x->bf16 ----------------

__global__ __launch_bounds__(256) void gate_topk(const float* __restrict__ x,
                                                 const float* __restrict__ Wg,
                                                 const float* __restrict__ bg,
                                                 int* __restrict__ eidx,
                                                 float* __restrict__ ewt,
                                                 unsigned short* __restrict__ xb) {
    const int t = blockIdx.x * 4 + (threadIdx.x >> 6);
    const int l = threadIdx.x & 63;
    const float* xr = x + (size_t)t * H_DIM;
    unsigned short* xw = xb + (size_t)t * H_DIM;
    double part[E_NUM];
#pragma unroll
    for (int e = 0; e < E_NUM; ++e) part[e] = 0.0;
#pragma unroll
    for (int i = 0; i < 8; ++i) {
        const int h = l + 64 * i;
        const float xv = xr[h];
        xw[h] = f2bf(xv);
        const double xd = (double)xv;
        const float* wr = Wg + (size_t)h * E_NUM;
#pragma unroll
        for (int e = 0; e < E_NUM; ++e) part[e] += xd * (double)wr[e];
    }
    for (int s = 1; s < 64; s <<= 1) {
#pragma unroll
        for (int e = 0; e < E_NUM; ++e) part[e] += __shfl_xor(part[e], s);
    }
    if (l == 0) {
        double lg[E_NUM];
#pragma unroll
        for (int e = 0; e < E_NUM; ++e) lg[e] = part[e] + (double)bg[e];
        int e0 = 0;
        for (int e = 1; e < E_NUM; ++e) if (lg[e] > lg[e0]) e0 = e;
        int e1 = (e0 == 0) ? 1 : 0;
        for (int e = 0; e < E_NUM; ++e) if (e != e0 && lg[e] > lg[e1]) e1 = e;
        double z = exp(lg[e1] - lg[e0]);
        float w0 = (float)(1.0 / (1.0 + z));
        float w1 = (float)(z / (1.0 + z));
        eidx[2 * t] = e0; eidx[2 * t + 1] = e1;
        ewt[2 * t] = w0; ewt[2 * t + 1] = w1;
    }
}

// ---------------- hierarchical routing scan ----------------

__global__ __launch_bounds__(256) void count_blocks(const int* __restrict__ eidx,
                                                    int* __restrict__ blockcnt) {
    __shared__ int cnt[E_NUM];
    if (threadIdx.x < E_NUM) cnt[threadIdx.x] = 0;
    __syncthreads();
    const int s = blockIdx.x * 256 + threadIdx.x;
    atomicAdd(&cnt[eidx[s]], 1);
    __syncthreads();
    if (threadIdx.x < E_NUM)
        blockcnt[blockIdx.x * E_NUM + threadIdx.x] = cnt[threadIdx.x];
}

__global__ __launch_bounds__(512) void scan_blocks(const int* __restrict__ blockcnt,
                                                   int* __restrict__ bbase,
                                                   int* __restrict__ offsets) {
    __shared__ int tot[E_NUM];
    __shared__ int obase[E_NUM + 1];
    const int e = threadIdx.x >> 6;
    const int l = threadIdx.x & 63;
    const int a = blockcnt[(2 * l) * E_NUM + e];
    const int b = blockcnt[(2 * l + 1) * E_NUM + e];
    const int s = a + b;
    int sc = s;
    for (int d = 1; d < 64; d <<= 1) {
        int o = __shfl_up(sc, d);
        if (l >= d) sc += o;
    }
    const int excl = sc - s;
    if (l == 63) tot[e] = sc;
    __syncthreads();
    if (threadIdx.x == 0) {
        int acc = 0;
        for (int i = 0; i < E_NUM; ++i) { obase[i] = acc; acc += tot[i]; }
        obase[E_NUM] = acc;
        for (int i = 0; i <= E_NUM; ++i) offsets[i] = obase[i];
    }
    __syncthreads();
    const int base = obase[e] + excl;
    bbase[(2 * l) * E_NUM + e] = base;
    bbase[(2 * l + 1) * E_NUM + e] = base + a;
}

__global__ __launch_bounds__(256) void scatter_slots(const int* __restrict__ eidx,
                                                     const float* __restrict__ ewt,
                                                     const int* __restrict__ bbase,
                                                     int* __restrict__ slot_token,
                                                     float* __restrict__ slot_w,
                                                     int* __restrict__ slot_of) {
    __shared__ int cur[E_NUM];
    if (threadIdx.x < E_NUM)
        cur[threadIdx.x] = bbase[blockIdx.x * E_NUM + threadIdx.x];
    __syncthreads();
    const int s = blockIdx.x * 256 + threadIdx.x;
    const int e = eidx[s];
    const int pos = atomicAdd(&cur[e], 1);
    slot_token[pos] = s >> 1;
    slot_w[pos] = ewt[s];
    slot_of[s] = pos;
}

// ---------------- grouped GEMM, 128x128 tile, BK=64, 8 waves, dbuf --------
// EPI=0: Hout[slot][c] = silu(A@B + bias)                  (bf16 packed x2)
// EPI=1: out[token][c] += slot_w*(A@B + bias)              (atomic fallback)
// EPI=2: Hout[slot][c] = bf16(slot_w*(A@B + bias))         (Yh, combine later)
// GAT=1: A rows gathered via slot_token.
// Wave grid 2m x 4n; per wave 64x32 = acc[4][2]. Lane l, wave-quarter wq:
// output cols c0..c0+1 with c0 = 64*(wq>>1) + 4*(l&15) + 2*(wq&1).
// Per K-step: {stage(kt+1)->buf^1 issued FIRST; ds_read+MFMA; __syncthreads}.
// B row permutation pi(64q+16j+m)=64q+4m+j (valid on both 64-row groups).

template<int EPI, int GAT, int NT, int KD, int NTOT, int MC, int LDA>
__global__ __launch_bounds__(512) void ggemm(
    const unsigned short* __restrict__ Ag,
    const unsigned short* __restrict__ Bt,
    const float* __restrict__ bias,
    const int* __restrict__ slot_token,
    const float* __restrict__ slot_w,
    const int* __restrict__ offsets,
    unsigned short* __restrict__ Hout,
    float* __restrict__ out) {
    const int e = blockIdx.x;
    const int nt = blockIdx.y % NT;
    const int mc = blockIdx.y / NT;
    const int base = offsets[e];
    const int cnt = offsets[e + 1] - base;
    if (cnt == 0) return;
    const int n0 = nt * 128;

    __shared__ __align__(16) unsigned short Abuf[2][128 * 64];
    __shared__ __align__(16) unsigned short Bbuf[2][128 * 64];

    const int tid = threadIdx.x;
    const int w = tid >> 6;
    const int l = tid & 63;
    const int wm = (w >> 2) << 6;   // 0 / 64
    const int wq = w & 3;
    const int wn = wq << 5;         // 0 / 32 / 64 / 96 (B fragment row base)

    // fragment LDS byte offsets for K-half 0; K-half 1 = offset ^ 64
    int aoff[4], boff[2];
#pragma unroll
    for (int i = 0; i < 4; ++i) {
        int r = wm + i * 16 + (l & 15);
        aoff[i] = r * 128 + ((((l >> 4) ^ (r & 7))) << 4);
    }
#pragma unroll
    for (int j = 0; j < 2; ++j) {
        int r = wn + j * 16 + (l & 15);
        boff[j] = r * 128 + ((((l >> 4) ^ (r & 7))) << 4);
    }

    const int srow = tid >> 3;           // 0..63, staging row within 64-row stripe
    const int sce = (tid & 7) * 8;       // staging LDS col (elements)
    const unsigned short* Bg = Bt + (size_t)e * NTOT * KD + (size_t)n0 * KD;
    const int nk = KD / 64;

    // permuted B source rows: LDS row rho holds global row pi(rho)
    int bsrc[2];
#pragma unroll
    for (int p = 0; p < 2; ++p) {
        int row = p * 64 + srow;
        bsrc[p] = (row & ~63) | ((row & 15) << 2) | ((row >> 4) & 3);
    }

    for (int m0 = mc * 128; m0 < cnt; m0 += MC * 128) {
        int arow[2];
#pragma unroll
        for (int p = 0; p < 2; ++p) {
            int s = m0 + p * 64 + srow;
            if (s > cnt - 1) s = cnt - 1;
            arow[p] = GAT ? slot_token[base + s] : (base + s);
        }

        // prologue: stage kt=0 into buf 0
#pragma unroll
        for (int p = 0; p < 2; ++p) {
            int row = p * 64 + srow;
            int ce = sce ^ ((row & 7) * 8);
            gload_lds16(Ag + (size_t)arow[p] * LDA + ce, &Abuf[0][row * 64 + sce]);
            gload_lds16(Bg + (size_t)bsrc[p] * KD + ce, &Bbuf[0][row * 64 + sce]);
        }
        __syncthreads();

        f32x4 acc[4][2] = {};
        for (int kt = 0; kt < nk; ++kt) {
            const int cur = kt & 1;
            if (kt + 1 < nk) {                   // issue next-tile stage FIRST
                const int k0 = (kt + 1) * 64;
#pragma unroll
                for (int p = 0; p < 2; ++p) {
                    int row = p * 64 + srow;
                    int ce = sce ^ ((row & 7) * 8);
                    gload_lds16(Ag + (size_t)arow[p] * LDA + k0 + ce, &Abuf[cur ^ 1][row * 64 + sce]);
                    gload_lds16(Bg + (size_t)bsrc[p] * KD + k0 + ce, &Bbuf[cur ^ 1][row * 64 + sce]);
                }
            }
            const char* Ab = (const char*)&Abuf[cur][0];
            const char* Bb = (const char*)&Bbuf[cur][0];
#pragma unroll
            for (int half = 0; half < 2; ++half) {
                const int kb = half << 6;
                s16x8 af[4], bfv[2];
#pragma unroll
                for (int i = 0; i < 4; ++i) af[i] = *(const s16x8*)(Ab + (aoff[i] ^ kb));
#pragma unroll
                for (int j = 0; j < 2; ++j) bfv[j] = *(const s16x8*)(Bb + (boff[j] ^ kb));
#pragma unroll
                for (int i = 0; i < 4; ++i)
#pragma unroll
                    for (int j = 0; j < 2; ++j)
                        acc[i][j] = __builtin_amdgcn_mfma_f32_16x16x32_bf16(af[i], bfv[j], acc[i][j], 0, 0, 0);
            }
            __syncthreads();   // drains this step's stage + orders buffers
        }

        // output cols: c0, c0+1
        const int c0 = ((wq >> 1) << 6) + (l & 15) * 4 + ((wq & 1) << 1);
        float b2v[2];
#pragma unroll
        for (int j = 0; j < 2; ++j) b2v[j] = bias[(size_t)e * NTOT + n0 + c0 + j];

#pragma unroll
        for (int i = 0; i < 4; ++i) {
            const int rb = wm + i * 16 + ((l >> 4) << 2);
#pragma unroll
            for (int r = 0; r < 4; ++r) {
                const int row = m0 + rb + r;
                if (row >= cnt) continue;
                const int slot = base + row;
                if (EPI == 0) {
                    float v0 = acc[i][0][r] + b2v[0];
                    float v1 = acc[i][1][r] + b2v[1];
                    v0 = v0 / (1.0f + __expf(-v0));
                    v1 = v1 / (1.0f + __expf(-v1));
                    unsigned int pk = (unsigned int)f2bf(v0) | ((unsigned int)f2bf(v1) << 16);
                    *(unsigned int*)&Hout[(size_t)slot * NTOT + n0 + c0] = pk;
                } else if (EPI == 2) {
                    const float wgt = slot_w[slot];
                    unsigned int pk = (unsigned int)f2bf(wgt * (acc[i][0][r] + b2v[0]))
                                    | ((unsigned int)f2bf(wgt * (acc[i][1][r] + b2v[1])) << 16);
                    *(unsigned int*)&Hout[(size_t)slot * NTOT + n0 + c0] = pk;
                } else {
                    const int tok = slot_token[slot];
                    const float wgt = slot_w[slot];
                    float* op = out + (size_t)tok * NTOT + n0 + c0;
#pragma unroll
                    for (int j = 0; j < 2; ++j)
                        atomicAdd(op + j, wgt * (acc[i][j][r] + b2v[j]));
                }
            }
        }
        __syncthreads();   // epilogue done before next m0 prologue overwrites buf0
    }
}

// out[t] = Yh[slot_of[2t]] + Yh[slot_of[2t+1]]   (bf16 in, f32 out)
__global__ __launch_bounds__(256) void combine_y(const unsigned short* __restrict__ Y,
                                                 const int* __restrict__ slot_of,
                                                 float* __restrict__ out) {
    const int idx = blockIdx.x * 256 + threadIdx.x;
    const int t = idx >> 6;
    const int h = (idx & 63) * 8;
    const int sa = slot_of[2 * t];
    const int sb = slot_of[2 * t + 1];
    s16x8 a = *(const s16x8*)&Y[(size_t)sa * H_DIM + h];
    s16x8 b = *(const s16x8*)&Y[(size_t)sb * H_DIM + h];
    f32x4 lo, hi;
#pragma unroll
    for (int j = 0; j < 4; ++j) {
        lo[j] = bf2f((unsigned short)a[j]) + bf2f((unsigned short)b[j]);
        hi[j] = bf2f((unsigned short)a[j + 4]) + bf2f((unsigned short)b[j + 4]);
    }
    float* po = out + (size_t)t * H_DIM + h;
    *(f32x4*)po = lo;
    *(f32x4*)(po + 4) = hi;
}

// ---------------- host ----------------

extern "C" void kernel_launch(void* const* d_in, const int* in_sizes, int n_in,
                              void* d_out, int out_size, void* d_ws, size_t ws_size,
                              hipStream_t stream) {
    const float* x  = (const float*)d_in[0];
    const float* Wg = (const float*)d_in[1];
    const float* bg = (const float*)d_in[2];
    const float* W1 = (const float*)d_in[3];
    const float* b1 = (const float*)d_in[4];
    const float* W2 = (const float*)d_in[5];
    const float* b2 = (const float*)d_in[6];
    float* out = (float*)d_out;

    char* ws = (char*)d_ws;
    size_t off = 0;
    auto take = [&](size_t b) -> void* {
        void* p = ws + off;
        off = (off + b + 255) & ~(size_t)255;
        return p;
    };
    unsigned short* xb   = (unsigned short*)take((size_t)T_TOK * H_DIM * 2);
    unsigned short* W1t  = (unsigned short*)take((size_t)E_NUM * H_DIM * FF_DIM * 2);
    unsigned short* W2t  = (unsigned short*)take((size_t)E_NUM * H_DIM * FF_DIM * 2);
    int*   eidx       = (int*)take((size_t)T_TOK * 2 * 4);
    float* ewt        = (float*)take((size_t)T_TOK * 2 * 4);
    int*   slot_token = (int*)take((size_t)NSLOT * 4);
    float* slot_w     = (float*)take((size_t)NSLOT * 4);
    int*   slot_of    = (int*)take((size_t)NSLOT * 4);
    int*   blockcnt   = (int*)take((size_t)NB_ROUTE * E_NUM * 4);
    int*   bbase      = (int*)take((size_t)NB_ROUTE * E_NUM * 4);
    int*   offsets    = (int*)take(256);
    unsigned short* Hact = (unsigned short*)take((size_t)NSLOT * FF_DIM * 2);
    unsigned short* Yh = (unsigned short*)(ws + off);
    const int useY = (ws_size >= off + (size_t)NSLOT * H_DIM * 2) ? 1 : 0;

    // fused weight transposes (f32 -> bf16, [E][C][R])
    transpose_both<<<dim3(64, 16, 16), 256, 0, stream>>>(W1, W2, W1t, W2t);

    // gating (+ fused x->bf16) + hierarchical routing (no global atomics)
    gate_topk<<<T_TOK / 4, 256, 0, stream>>>(x, Wg, bg, eidx, ewt, xb);
    count_blocks<<<NB_ROUTE, 256, 0, stream>>>(eidx, blockcnt);
    scan_blocks<<<1, 512, 0, stream>>>(blockcnt, bbase, offsets);
    scatter_slots<<<NB_ROUTE, 256, 0, stream>>>(eidx, ewt, bbase, slot_token, slot_w, slot_of);

    // GEMM1: M=cnt, N=2048, K=512.  grid (8, 16 nt x 16 mc) = 2048 blocks
    ggemm<0, 1, 16, 512, 2048, 16, 512><<<dim3(8, 256), 512, 0, stream>>>(
        xb, W1t, b1, slot_token, slot_w, offsets, Hact, out);
    // GEMM2: M=cnt, N=512, K=2048.  grid (8, 4 nt x 32 mc) = 1024 blocks
    if (useY) {
        ggemm<2, 0, 4, 2048, 512, 32, 2048><<<dim3(8, 128), 512, 0, stream>>>(
            Hact, W2t, b2, slot_token, slot_w, offsets, Yh, out);
        combine_y<<<T_TOK * 64 / 256, 256, 0, stream>>>(Yh, slot_of, out);
    } else {
        zero_f32<<<(T_TOK * H_DIM / 4 + 255) / 256, 256, 0, stream>>>(out, T_TOK * H_DIM);
        ggemm<1, 0, 4, 2048, 512, 32, 2048><<<dim3(8, 128), 512, 0, stream>>>(
            Hact, W2t, b2, slot_token, slot_w, offsets, Hact, out);
    }
    (void)in_sizes; (void)n_in; (void)out_size;
}